// Round 3
// baseline (199.844 us; speedup 1.0000x reference)
//
#include <hip/hip_runtime.h>
#include <hip/hip_fp16.h>

#define NBINS 255
#define NPAIRS 32
#define BIGF 3.0e38f

// ws layout (float index):
//   [0     ,16384) : E    [64][256] fp32, tail BIGF
//   [16384 ,32768) : PE   [64][256]
//   [32768 ,36864) : M4E  [64][16] float4 {e[4j+3]} j=4t+c  (idx>=255 -> BIGF)
//   [36864 ,40960) : M4P
//   [40960 ,41984) : CU16 [64][16] coarse e[16j+15], j=15 pad BIGF
//   [41984 ,43008) : CP16
//   [43008 ,51200) : W16g [64][256] fp16 PRE-SHIFTED (8192 floats of storage)
//   byte 204800 .. : T16  [32][256][256] fp16 PRE-SHIFTED (needs ws >= 4399104 B)

__global__ void ebm_prep(const float* __restrict__ edges,
                         const float* __restrict__ pair_edges,
                         const float* __restrict__ w,
                         float* __restrict__ ws) {
    int tid = blockIdx.x * blockDim.x + threadIdx.x;  // 16384 threads
    int f = tid >> 8, j = tid & 255;
    float* E  = ws;
    float* PE = ws + 16384;
    float* ME = ws + 32768;
    float* MP = ws + 36864;
    float* CU = ws + 40960;
    float* CP = ws + 41984;
    __half* W = (__half*)(ws + 43008);
    E[tid]  = (j < NBINS) ? edges[f * NBINS + j]      : BIGF;
    PE[tid] = (j < NBINS) ? pair_edges[f * NBINS + j] : BIGF;
    int src = (j < 255) ? j + 1 : 0;
    W[tid]  = __float2half(w[f * 256 + src]);
    if (j < 64) {
        int idx = 4 * j + 3;   // j=4t+c -> e[16t+4c+3]
        ME[f * 64 + j] = (idx < NBINS) ? edges[f * NBINS + idx]      : BIGF;
        MP[f * 64 + j] = (idx < NBINS) ? pair_edges[f * NBINS + idx] : BIGF;
    }
    if (j < 16) {
        CU[f * 16 + j] = (j < 15) ? edges[f * NBINS + 16 * j + 15]      : BIGF;
        CP[f * 16 + j] = (j < 15) ? pair_edges[f * NBINS + 16 * j + 15] : BIGF;
    }
}

__global__ void ebm_prep_tables(const float* __restrict__ tables,
                                unsigned short* __restrict__ o) {
    int i = blockIdx.x * blockDim.x + threadIdx.x;    // 2097152 threads
    int b = i & 255, a = (i >> 8) & 255, p = i >> 16;
    int ra = (a < 255) ? a + 1 : 0;
    int rb = (b < 255) ? b + 1 : 0;
    o[i] = __half_as_ushort(__float2half(tables[(p << 16) + (ra << 8) + rb]));
}

// uniform 16-way register select: s is wave-uniform -> 15 v_cndmask w/ scalar masks
__device__ __forceinline__ unsigned pick16(const unsigned* pw, int s) {
    unsigned v01 = (s & 1) ? pw[1]  : pw[0];
    unsigned v23 = (s & 1) ? pw[3]  : pw[2];
    unsigned v45 = (s & 1) ? pw[5]  : pw[4];
    unsigned v67 = (s & 1) ? pw[7]  : pw[6];
    unsigned v89 = (s & 1) ? pw[9]  : pw[8];
    unsigned vab = (s & 1) ? pw[11] : pw[10];
    unsigned vcd = (s & 1) ? pw[13] : pw[12];
    unsigned vef = (s & 1) ? pw[15] : pw[14];
    unsigned w0 = (s & 2) ? v23 : v01;
    unsigned w1 = (s & 2) ? v67 : v45;
    unsigned w2 = (s & 2) ? vab : v89;
    unsigned w3 = (s & 2) ? vef : vcd;
    unsigned u0 = (s & 4) ? w1 : w0;
    unsigned u1 = (s & 4) ? w3 : w2;
    return (s & 8) ? u1 : u0;
}

// v4: v3 structure, but the coarse tables (CU/CP) are read from GLOBAL memory
// (uniform-address dwordx4 -> one coalesced request/wave, L1/L2-hot) instead of
// SMEM s_loads. This makes the lgkmcnt domain PURE-DS: on gfx9-lineage, mixed
// SMEM+DS completes out of order so only lgkmcnt(0) full drains are safe —
// which serialized every mid/fine consume in v1-v3 (VALUBusy pinned at 50%
// regardless of ILP or occupancy). With pure-DS lgkm, the compiler can emit
// counted in-order lgkmcnt(N) waits and actually pipeline the 8-wide batches.
__global__ __launch_bounds__(1024, 4) void ebm_main(
    const float* __restrict__ x,
    const int*   __restrict__ pairs,
    const float* __restrict__ tables_f32,
    const float* __restrict__ bias,
    const float* __restrict__ ws,
    const __half* __restrict__ T16,
    int useT16,
    float*       __restrict__ out) {

    // exactly 160 KiB
    __shared__ float  sE[16384];
    __shared__ float  sPE[16384];
    __shared__ float4 sME[1024];
    __shared__ float4 sMP[1024];

    int tid = threadIdx.x;
    {
        const float4* w4 = (const float4*)ws;
        float4* dE = (float4*)sE;
        float4* dP = (float4*)sPE;
        for (int i = tid; i < 4096; i += 1024) {
            dE[i] = w4[i];
            dP[i] = w4[4096 + i];
        }
        sME[tid] = w4[8192 + tid];
        sMP[tid] = w4[9216 + tid];
    }
    const float4* CU4 = (const float4*)(ws + 40960);   // [64][4] float4, global (vmcnt domain)
    const float4* CP4 = (const float4*)(ws + 41984);
    const __half* Wg  = (const __half*)(ws + 43008);
    float bias0 = bias[0];

    __syncthreads();

    int row = blockIdx.x * 1024 + tid;       // 256 blocks x 1024 threads
    const float4* x4  = (const float4*)x + row * 16;
    const float4* sE4 = (const float4*)sE;
    const float4* sP4 = (const float4*)sPE;

    float acc = 0.f;
    unsigned pw[16];

    float4 xa = x4[0];
    float4 xb = x4[1];
#pragma unroll
    for (int gg = 0; gg < 8; ++gg) {
        int fb = gg * 8;                      // feature base (compile-time per iter)
        float4 xan = xa, xbn = xb;
        if (gg < 7) { xan = x4[2 * gg + 2]; xbn = x4[2 * gg + 3]; }
        float xf[8] = {xa.x, xa.y, xa.z, xa.w, xb.x, xb.y, xb.z, xb.w};

        // ---- coarse: unary then pair (global uniform loads + VALU compares) ----
        int t[8], t2[8];
#pragma unroll
        for (int j = 0; j < 8; ++j) {
            float4 c0 = CU4[(fb + j) * 4 + 0];
            float4 c1 = CU4[(fb + j) * 4 + 1];
            float4 c2 = CU4[(fb + j) * 4 + 2];
            float4 c3 = CU4[(fb + j) * 4 + 3];   // .w = BIGF pad (never true)
            float xv = xf[j];
            int tt = (xv >= c0.x) + (xv >= c0.y) + (xv >= c0.z) + (xv >= c0.w)
                   + (xv >= c1.x) + (xv >= c1.y) + (xv >= c1.z) + (xv >= c1.w)
                   + (xv >= c2.x) + (xv >= c2.y) + (xv >= c2.z) + (xv >= c2.w)
                   + (xv >= c3.x) + (xv >= c3.y) + (xv >= c3.z);
            t[j] = tt;
        }
#pragma unroll
        for (int j = 0; j < 8; ++j) {
            float4 c0 = CP4[(fb + j) * 4 + 0];
            float4 c1 = CP4[(fb + j) * 4 + 1];
            float4 c2 = CP4[(fb + j) * 4 + 2];
            float4 c3 = CP4[(fb + j) * 4 + 3];
            float xv = xf[j];
            int tt = (xv >= c0.x) + (xv >= c0.y) + (xv >= c0.z) + (xv >= c0.w)
                   + (xv >= c1.x) + (xv >= c1.y) + (xv >= c1.z) + (xv >= c1.w)
                   + (xv >= c2.x) + (xv >= c2.y) + (xv >= c2.z) + (xv >= c2.w)
                   + (xv >= c3.x) + (xv >= c3.y) + (xv >= c3.z);
            t2[j] = tt;
        }
        // ---- mids: 16 ds_read_b128 in flight (pure-DS lgkm from here) ----
        float4 mu[8], mp[8];
#pragma unroll
        for (int j = 0; j < 8; ++j) mu[j] = sME[(fb + j) * 16 + t[j]];
#pragma unroll
        for (int j = 0; j < 8; ++j) mp[j] = sMP[(fb + j) * 16 + t2[j]];
        // ---- fines: 16 ds_read_b128 in flight ----
        int lo[8], lo2[8];
        float4 fu[8], fp[8];
#pragma unroll
        for (int j = 0; j < 8; ++j) {
            int m = (xf[j] >= mu[j].x) + (xf[j] >= mu[j].y) + (xf[j] >= mu[j].z);
            lo[j] = 4 * t[j] + m;
            fu[j] = sE4[(fb + j) * 64 + lo[j]];
        }
#pragma unroll
        for (int j = 0; j < 8; ++j) {
            int m = (xf[j] >= mp[j].x) + (xf[j] >= mp[j].y) + (xf[j] >= mp[j].z);
            lo2[j] = 4 * t2[j] + m;
            fp[j] = sP4[(fb + j) * 64 + lo2[j]];
        }
        // ---- unary consume -> W gather (global fp16, latency-tolerant) ----
#pragma unroll
        for (int j = 0; j < 8; ++j) {
            int c = 4 * lo[j] + (xf[j] >= fu[j].x) + (xf[j] >= fu[j].y) +
                    (xf[j] >= fu[j].z) + (xf[j] >= fu[j].w);
            acc += __half2float(Wg[(fb + j) * 256 + c]);
        }
        // ---- pair consume -> pack two 4x8-bit words ----
        unsigned p0 = 0, p1 = 0;
#pragma unroll
        for (int j = 0; j < 4; ++j) {
            int c2 = 4 * lo2[j] + (xf[j] >= fp[j].x) + (xf[j] >= fp[j].y) +
                     (xf[j] >= fp[j].z) + (xf[j] >= fp[j].w);
            p0 |= (unsigned)c2 << (8 * j);
        }
#pragma unroll
        for (int j = 4; j < 8; ++j) {
            int c2 = 4 * lo2[j] + (xf[j] >= fp[j].x) + (xf[j] >= fp[j].y) +
                     (xf[j] >= fp[j].z) + (xf[j] >= fp[j].w);
            p1 |= (unsigned)c2 << (8 * (j - 4));
        }
        pw[2 * gg]     = p0;
        pw[2 * gg + 1] = p1;
        xa = xan; xb = xbn;
    }

    // ---- pair table gathers: per-lane-owned, no exchange ----
    if (useT16) {
#pragma unroll
        for (int p = 0; p < NPAIRS; ++p) {
            int a = pairs[2 * p], b = pairs[2 * p + 1];   // uniform
            unsigned wa = pick16(pw, a >> 2);
            unsigned wb = pick16(pw, b >> 2);
            int li = (wa >> ((a & 3) * 8)) & 255;
            int ri = (wb >> ((b & 3) * 8)) & 255;
            acc += __half2float(T16[(p << 16) + (li << 8) + ri]);
        }
    } else {
#pragma unroll
        for (int p = 0; p < NPAIRS; ++p) {
            int a = pairs[2 * p], b = pairs[2 * p + 1];
            unsigned wa = pick16(pw, a >> 2);
            unsigned wb = pick16(pw, b >> 2);
            int li = (wa >> ((a & 3) * 8)) & 255;
            int ri = (wb >> ((b & 3) * 8)) & 255;
            int lb = (li < 255) ? li + 1 : 0;
            int rb = (ri < 255) ? ri + 1 : 0;
            acc += tables_f32[(p << 16) + (lb << 8) + rb];
        }
    }

    out[row] = 1.0f / (1.0f + __expf(-(acc + bias0)));
}

extern "C" void kernel_launch(void* const* d_in, const int* in_sizes, int n_in,
                              void* d_out, int out_size, void* d_ws, size_t ws_size,
                              hipStream_t stream) {
    const float* x          = (const float*)d_in[0];
    const float* edges      = (const float*)d_in[1];
    const float* w          = (const float*)d_in[2];
    const float* pair_edges = (const float*)d_in[3];
    const int*   pairs      = (const int*)d_in[4];
    const float* tables     = (const float*)d_in[5];
    const float* bias       = (const float*)d_in[6];
    float* out = (float*)d_out;
    float* ws  = (float*)d_ws;

    int useT16 = (ws_size >= (size_t)4399104) ? 1 : 0;
    __half* T16 = (__half*)((char*)d_ws + 204800);

    ebm_prep<<<64, 256, 0, stream>>>(edges, pair_edges, w, ws);
    if (useT16) {
        ebm_prep_tables<<<2048, 1024, 0, stream>>>(tables, (unsigned short*)T16);
    }
    ebm_main<<<256, 1024, 0, stream>>>(x, pairs, tables, bias, ws, T16, useT16, out);
}